// Round 5
// baseline (2826.807 us; speedup 1.0000x reference)
//
#include <hip/hip_runtime.h>

// ---------------- problem constants ----------------
#define T_LEN 128
// ws layout (bytes)
#define WPACK_OFF 0
#define BIAS_OFF 1310720
#define XF_OFF 1318912

typedef short bf16x8 __attribute__((ext_vector_type(8)));
typedef float f32x4 __attribute__((ext_vector_type(4)));
typedef unsigned int uint2v __attribute__((ext_vector_type(2)));

#define SCHB __builtin_amdgcn_sched_barrier(0)

__device__ __forceinline__ short f32_to_bf16(float f) {
  unsigned u = __float_as_uint(f);
  unsigned r = u + 0x7FFFu + ((u >> 16) & 1u);   // RNE
  return (short)(r >> 16);
}
__device__ __forceinline__ float sigmoidf_fast(float x) {
  return 1.0f / (1.0f + __expf(-x));
}
__device__ __forceinline__ float tanhf_fast(float x) {
  return 1.0f - 2.0f / (__expf(2.0f * x) + 1.0f);
}

// ---------------- prep: pack W fragment-major ----------------
// Wpack[dir][w][kt][mt][lane][8 bf16]; row = gt*256 + 32w + 16jt + (l&15),
// k = kt*32 + (l>>4)*8 + e  (k<64 -> W_ih, else W_hh col k-64)
__global__ void pack_w(const float* __restrict__ Wih_f, const float* __restrict__ Whh_f,
                       const float* __restrict__ Wih_b, const float* __restrict__ Whh_b,
                       short* __restrict__ wpack) {
  int t = blockIdx.x * blockDim.x + threadIdx.x;   // 81920 exact
  int l = t & 63; t >>= 6;
  int mt = t & 7; t >>= 3;
  int kt = t % 10; t /= 10;
  int w = t & 7;
  int dir = t >> 3;
  const float* Wih = dir ? Wih_b : Wih_f;
  const float* Whh = dir ? Whh_b : Whh_f;
  int gt = mt >> 1, jt = mt & 1;
  int row = gt * 256 + 32 * w + 16 * jt + (l & 15);
  int kbase = kt * 32 + (l >> 4) * 8;
  bf16x8 v;
#pragma unroll
  for (int e = 0; e < 8; ++e) {
    int k = kbase + e;
    float f = (k < 64) ? Wih[row * 64 + k] : Whh[row * 256 + (k - 64)];
    v[e] = f32_to_bf16(f);
  }
  long idx = ((((long)dir * 8 + w) * 10 + kt) * 8 + mt) * 64 + l;
  *reinterpret_cast<bf16x8*>(wpack + idx * 8) = v;
}

__global__ void pack_bias(const float* __restrict__ bihf, const float* __restrict__ bhhf,
                          const float* __restrict__ bihb, const float* __restrict__ bhhb,
                          float* __restrict__ bias) {
  int t = blockIdx.x * blockDim.x + threadIdx.x;
  if (t >= 2048) return;
  int dir = t >> 10, g = t & 1023;
  bias[t] = dir ? (bihb[g] + bhhb[g]) : (bihf[g] + bhhf[g]);
}

// xF[bg][t][kt][lane][8 bf16]: n = a0+(l&15), k(channel) = kt*32+(l>>4)*8+e
__global__ void pack_x(const float* __restrict__ x, short* __restrict__ xf) {
  int t = blockIdx.x * blockDim.x + threadIdx.x;   // 2^20 exact
  int l = t & 63; t >>= 6;
  int kt = t & 1; t >>= 1;
  int tt = t & 127; t >>= 7;
  int bg = t;
  int s = bg >> 2, a0 = (bg & 3) << 4;
  int cbase = kt * 32 + (l >> 4) * 8;
  int a = a0 + (l & 15);
  bf16x8 v;
#pragma unroll
  for (int e = 0; e < 8; ++e) {
    int c = cbase + e;
    v[e] = f32_to_bf16(x[(((long)s * 64 + c) * 128 + tt) * 64 + a]);
  }
  long idx = (((long)bg * 128 + tt) * 2 + kt) * 64 + l;
  *reinterpret_cast<bf16x8*>(xf + idx * 8) = v;
}

// ---------------- the recurrent kernel ----------------
// grid 128 (bid&1 = dir -> each XCD's L2 caches one dir's 640KB W pack),
// block 512 (8 waves). Wave w owns hidden slice [32w,32w+32) of all 4 gates.
// W streamed as 40 linear 2-frag chunks/step (chunk c = frags 2c,2c+1; kt=c>>2)
// through a 4-deep REGISTER ring (plain global loads, compiler-counted vmcnt),
// lookahead 3 chunks. Arithmetic order identical to R1/R2: bias, kt0, kt1,
// kt2..9 ascending. 2 raw barriers/step + single h LDS buffer (R3-proven).
__global__ __launch_bounds__(512) void lstm_rec(
    const short* __restrict__ wpack, const float* __restrict__ bias,
    const short* __restrict__ xf, float* __restrict__ out) {
  __shared__ __align__(16) short hbuf[16 * 256];   // 8KB single buffer
  __shared__ __align__(16) float bias_lds[1024];   // 4KB
  const int bid = blockIdx.x;
  const int dir = bid & 1, bg = bid >> 1;
  const int tid = threadIdx.x;
  const int w = tid >> 6, l = tid & 63;
  const int lg = l >> 4, ln = l & 15;
  const int s = bg >> 2, a0 = (bg & 3) << 4;

  for (int i = tid; i < 4096; i += 512) hbuf[i] = 0;
  for (int i = tid; i < 1024; i += 512) {
    int r = i & 3, mt = (i >> 2) & 7, lg_ = (i >> 5) & 3, w_ = i >> 7;
    int gt = mt >> 1, jt = mt & 1;
    int row = gt * 256 + 32 * w_ + 16 * jt + 4 * lg_ + r;
    bias_lds[i] = bias[dir * 1024 + row];
  }
  __syncthreads();

  // frag f of this wave's W slice at wp[f*64] (f = kt*8+mt, 0..79)
  const bf16x8* wp = reinterpret_cast<const bf16x8*>(wpack) +
                     ((long)dir * 8 + w) * 5120 + l;
  const char* xb = (const char*)xf + (long)bg * (128L * 2048) + (long)l * 16;

  float* outp = out + ((long)s * 512 + dir * 256) * 8192 + a0 + ln;
  float cst[2][4] = {{0.f, 0.f, 0.f, 0.f}, {0.f, 0.f, 0.f, 0.f}};
  const int swz = (ln & 7) << 4;
  const int bias_fidx = (w << 7) | (lg << 5);    // float index base

  // ---- prologue: x(t0) + first 3 W chunks into the register ring ----
  bf16x8 wr[4][2];
  bf16x8 bxc0, bxc1, bxn0, bxn1;
  {
    const int t0 = dir ? (T_LEN - 1) : 0;
    bxc0 = *reinterpret_cast<const bf16x8*>(xb + (long)t0 * 2048);
    bxc1 = *reinterpret_cast<const bf16x8*>(xb + (long)t0 * 2048 + 1024);
  }
#pragma unroll
  for (int c = 0; c < 3; ++c) {
    wr[c][0] = wp[(c * 2 + 0) * 64];
    wr[c][1] = wp[(c * 2 + 1) * 64];
  }

  // Per step: acc=bias; 40 chunks {issue c+3 -> ring, 2 MFMA from ring[c&3]};
  // epilogue; out stores; [barrier A]; h-write; [lgkm0; barrier B].
  // Ring state is steady across steps ((c+3)%40 wraps to next step's 0,1,2).
#define STEP(BXA0, BXA1, BXB0, BXB1, ST) do {                                 \
    const int t_ = dir ? (T_LEN - 1 - (ST)) : (ST);                           \
    const int tn_ = dir ? (t_ ? t_ - 1 : 0)                                   \
                        : (t_ < T_LEN - 1 ? t_ + 1 : T_LEN - 1);              \
    f32x4 acc[8];                                                             \
    _Pragma("unroll")                                                         \
    for (int mt_ = 0; mt_ < 8; ++mt_)                                         \
      acc[mt_] = *reinterpret_cast<const f32x4*>(bias_lds + bias_fidx + mt_ * 4); \
    bf16x8 bh_;                                                               \
    _Pragma("unroll")                                                         \
    for (int c = 0; c < 40; ++c) {                                            \
      const int cn_ = (c + 3) % 40;                                           \
      wr[(c + 3) & 3][0] = wp[(cn_ * 2 + 0) * 64];                            \
      wr[(c + 3) & 3][1] = wp[(cn_ * 2 + 1) * 64];                            \
      if (c == 8)  BXB0 = *reinterpret_cast<const bf16x8*>(xb + (long)tn_ * 2048); \
      if (c == 9)  BXB1 = *reinterpret_cast<const bf16x8*>(xb + (long)tn_ * 2048 + 1024); \
      if (c >= 8 && (c & 3) == 0)                                             \
        bh_ = *reinterpret_cast<const bf16x8*>(                               \
            (const char*)hbuf + 512 * ln + (((((c >> 2) - 2) * 64) + lg * 16) ^ swz)); \
      const bf16x8 b_ = (c < 8) ? ((c >> 2) ? BXA1 : BXA0) : bh_;             \
      acc[(2 * c) & 7] = __builtin_amdgcn_mfma_f32_16x16x32_bf16(             \
          wr[c & 3][0], b_, acc[(2 * c) & 7], 0, 0, 0);                       \
      acc[(2 * c + 1) & 7] = __builtin_amdgcn_mfma_f32_16x16x32_bf16(         \
          wr[c & 3][1], b_, acc[(2 * c + 1) & 7], 0, 0, 0);                   \
    }                                                                         \
    /* epilogue: gates -> c, h */                                             \
    float hv_[2][4];                                                          \
    _Pragma("unroll")                                                         \
    for (int jt_ = 0; jt_ < 2; ++jt_) {                                       \
      _Pragma("unroll")                                                       \
      for (int r_ = 0; r_ < 4; ++r_) {                                        \
        float gi_ = sigmoidf_fast(acc[0 + jt_][r_]);                          \
        float gf_ = sigmoidf_fast(acc[2 + jt_][r_]);                          \
        float gg_ = tanhf_fast(acc[4 + jt_][r_]);                             \
        float go_ = sigmoidf_fast(acc[6 + jt_][r_]);                          \
        float c_ = gf_ * cst[jt_][r_] + gi_ * gg_;                            \
        cst[jt_][r_] = c_;                                                    \
        hv_[jt_][r_] = go_ * tanhf_fast(c_);                                  \
      }                                                                       \
    }                                                                         \
    { /* out stores (f32, coalesced over ln) */                               \
      float* outt_ = outp + (long)t_ * 64;                                    \
      _Pragma("unroll")                                                       \
      for (int jt_ = 0; jt_ < 2; ++jt_)                                       \
        _Pragma("unroll")                                                     \
        for (int r_ = 0; r_ < 4; ++r_)                                        \
          outt_[(long)(32 * w + 16 * jt_ + 4 * lg + r_) * 8192] = hv_[jt_][r_]; \
    }                                                                         \
    /* barrier A: all waves done reading h(t-1) (reads already retired) */    \
    SCHB; __builtin_amdgcn_s_barrier(); SCHB;                                 \
    { /* h write: 2x ds_write_b64, swizzled (address-equiv to b16 writes) */  \
      char* hw_ = (char*)hbuf + 512 * ln;                                     \
      _Pragma("unroll")                                                       \
      for (int jt_ = 0; jt_ < 2; ++jt_) {                                     \
        unsigned lo_ = (unsigned short)f32_to_bf16(hv_[jt_][0]) |             \
                       ((unsigned)(unsigned short)f32_to_bf16(hv_[jt_][1]) << 16); \
        unsigned hi_ = (unsigned short)f32_to_bf16(hv_[jt_][2]) |             \
                       ((unsigned)(unsigned short)f32_to_bf16(hv_[jt_][3]) << 16); \
        uint2v v_ = {lo_, hi_};                                               \
        *reinterpret_cast<uint2v*>(                                           \
            hw_ + ((64 * w + 32 * jt_ + 8 * lg) ^ swz)) = v_;                 \
      }                                                                       \
    }                                                                         \
    /* barrier B: h visible before next step's reads */                       \
    asm volatile("s_waitcnt lgkmcnt(0)" ::: "memory");                        \
    __builtin_amdgcn_s_barrier();                                             \
    SCHB;                                                                     \
  } while (0)

  for (int sp = 0; sp < 64; ++sp) {
    STEP(bxc0, bxc1, bxn0, bxn1, 2 * sp);
    STEP(bxn0, bxn1, bxc0, bxc1, 2 * sp + 1);
  }
#undef STEP
}

// ---------------- launcher ----------------
extern "C" void kernel_launch(void* const* d_in, const int* in_sizes, int n_in,
                              void* d_out, int out_size, void* d_ws, size_t ws_size,
                              hipStream_t stream) {
  const float* x     = (const float*)d_in[0];
  const float* Wih_f = (const float*)d_in[1];
  const float* Whh_f = (const float*)d_in[2];
  const float* bih_f = (const float*)d_in[3];
  const float* bhh_f = (const float*)d_in[4];
  const float* Wih_b = (const float*)d_in[5];
  const float* Whh_b = (const float*)d_in[6];
  const float* bih_b = (const float*)d_in[7];
  const float* bhh_b = (const float*)d_in[8];
  float* out = (float*)d_out;

  char* ws = (char*)d_ws;
  short* wpack = (short*)(ws + WPACK_OFF);
  float* bias  = (float*)(ws + BIAS_OFF);
  short* xfb   = (short*)(ws + XF_OFF);

  hipLaunchKernelGGL(pack_w, dim3(320), dim3(256), 0, stream,
                     Wih_f, Whh_f, Wih_b, Whh_b, wpack);
  hipLaunchKernelGGL(pack_bias, dim3(8), dim3(256), 0, stream,
                     bih_f, bhh_f, bih_b, bhh_b, bias);
  hipLaunchKernelGGL(pack_x, dim3(4096), dim3(256), 0, stream, x, xfb);
  hipLaunchKernelGGL(lstm_rec, dim3(128), dim3(512), 0, stream,
                     wpack, bias, xfb, out);
}

// Round 7
// 1164.959 us; speedup vs baseline: 2.4265x; 2.4265x over previous
//
#include <hip/hip_runtime.h>

// ---------------- problem constants ----------------
#define T_LEN 128
// ws layout (bytes)
#define WPACK_OFF 0
#define BIAS_OFF 1310720
#define XF_OFF 1318912

typedef short bf16x8 __attribute__((ext_vector_type(8)));
typedef float f32x4 __attribute__((ext_vector_type(4)));
typedef unsigned int uint2v __attribute__((ext_vector_type(2)));

// ---- LDS layout (bytes), dynamic shared ----
#define L_RING 0          // 8 waves * 8 slots * 2KB = 131072
#define L_H    131072     // 16 rows * 512B = 8192 (single-buffered)
#define L_BIAS 139264     // 4096
#define SMEM_BYTES 143360

#define WAITV(n) asm volatile("s_waitcnt vmcnt(" #n ")" ::: "memory")
#define SCHB __builtin_amdgcn_sched_barrier(0)

__device__ __forceinline__ short f32_to_bf16(float f) {
  unsigned u = __float_as_uint(f);
  unsigned r = u + 0x7FFFu + ((u >> 16) & 1u);   // RNE
  return (short)(r >> 16);
}
__device__ __forceinline__ float sigmoidf_fast(float x) {
  return 1.0f / (1.0f + __expf(-x));
}
__device__ __forceinline__ float tanhf_fast(float x) {
  return 1.0f - 2.0f / (__expf(2.0f * x) + 1.0f);
}

// async 16B/lane global->LDS DMA (wave-uniform LDS base + lane*16)
__device__ __forceinline__ void gll16(const void* g, char* lds_generic) {
  __builtin_amdgcn_global_load_lds(
      (const __attribute__((address_space(1))) void*)g,
      (__attribute__((address_space(3))) void*)lds_generic, 16, 0, 0);
}

// ---------------- prep: pack W fragment-major ----------------
// Wpack[dir][w][kt][mt][lane][8 bf16]; row = gt*256 + 32w + 16jt + (l&15),
// k = kt*32 + (l>>4)*8 + e  (k<64 -> W_ih, else W_hh col k-64)
__global__ void pack_w(const float* __restrict__ Wih_f, const float* __restrict__ Whh_f,
                       const float* __restrict__ Wih_b, const float* __restrict__ Whh_b,
                       short* __restrict__ wpack) {
  int t = blockIdx.x * blockDim.x + threadIdx.x;   // 81920 exact
  int l = t & 63; t >>= 6;
  int mt = t & 7; t >>= 3;
  int kt = t % 10; t /= 10;
  int w = t & 7;
  int dir = t >> 3;
  const float* Wih = dir ? Wih_b : Wih_f;
  const float* Whh = dir ? Whh_b : Whh_f;
  int gt = mt >> 1, jt = mt & 1;
  int row = gt * 256 + 32 * w + 16 * jt + (l & 15);
  int kbase = kt * 32 + (l >> 4) * 8;
  bf16x8 v;
#pragma unroll
  for (int e = 0; e < 8; ++e) {
    int k = kbase + e;
    float f = (k < 64) ? Wih[row * 64 + k] : Whh[row * 256 + (k - 64)];
    v[e] = f32_to_bf16(f);
  }
  long idx = ((((long)dir * 8 + w) * 10 + kt) * 8 + mt) * 64 + l;
  *reinterpret_cast<bf16x8*>(wpack + idx * 8) = v;
}

__global__ void pack_bias(const float* __restrict__ bihf, const float* __restrict__ bhhf,
                          const float* __restrict__ bihb, const float* __restrict__ bhhb,
                          float* __restrict__ bias) {
  int t = blockIdx.x * blockDim.x + threadIdx.x;
  if (t >= 2048) return;
  int dir = t >> 10, g = t & 1023;
  bias[t] = dir ? (bihb[g] + bhhb[g]) : (bihf[g] + bhhf[g]);
}

// xF[bg][t][kt][lane][8 bf16]: n = a0+(l&15), k(channel) = kt*32+(l>>4)*8+e
__global__ void pack_x(const float* __restrict__ x, short* __restrict__ xf) {
  int t = blockIdx.x * blockDim.x + threadIdx.x;   // 2^20 exact
  int l = t & 63; t >>= 6;
  int kt = t & 1; t >>= 1;
  int tt = t & 127; t >>= 7;
  int bg = t;
  int s = bg >> 2, a0 = (bg & 3) << 4;
  int cbase = kt * 32 + (l >> 4) * 8;
  int a = a0 + (l & 15);
  bf16x8 v;
#pragma unroll
  for (int e = 0; e < 8; ++e) {
    int c = cbase + e;
    v[e] = f32_to_bf16(x[(((long)s * 64 + c) * 128 + tt) * 64 + a]);
  }
  long idx = (((long)bg * 128 + tt) * 2 + kt) * 64 + l;
  *reinterpret_cast<bf16x8*>(xf + idx * 8) = v;
}

// ---------------- the recurrent kernel ----------------
// grid 128 (bid&1 = dir -> each XCD's L2 caches one dir's 640KB W pack),
// block 512 (8 waves, waves_per_eu(2,2) -> 256-VGPR budget). Wave w owns
// hidden slice [32w,32w+32) of all 4 gates (8 mt frags), K = 320 (10 kt).
// kt2..5 PERSIST in registers (32 frags, loaded once). kt6..9 + kt0,1 stream
// via LDS DMA ring: granule = 2 frags (2KB/wave), 8 slots, lookahead 6.
// Issue schedule (per step): prologue/prev-step issued g0..g5; phase3 iter c
// issues g(c+6) (c=0..15 -> g6..g21); phase5 c=16 -> g22, c=17 -> g23,
// c=18..23 -> NEXT step's g0..g5 (addresses step-invariant).
// Ledger: every granule has exactly 6 granules (12 ops) issued after it
// before its WAITV(12); in-order VMEM retire => target granule landed.
// bx loads / out stores only over-wait (they add to issued-after count).
// Slot reuse distance >= 2 consume-iterations everywhere (program order:
// consume ds_read completes -> its MFMA issues -> later re-issue DMA).
// Accumulation order kt2..9 then kt0,1 == R3 -> absmax bit-identical.
__global__ __launch_bounds__(512) __attribute__((amdgpu_waves_per_eu(2, 2)))
void lstm_rec(const short* __restrict__ wpack, const float* __restrict__ bias,
              const short* __restrict__ xf, float* __restrict__ out) {
  extern __shared__ char smem[];
  const int bid = blockIdx.x;
  const int dir = bid & 1, bg = bid >> 1;
  const int tid = threadIdx.x;
  const int w = tid >> 6, l = tid & 63;
  const int lg = l >> 4, ln = l & 15;
  const int s = bg >> 2, a0 = (bg & 3) << 4;

  // zero h, fill bias table
  for (int i = tid; i < 4096; i += 512) ((short*)(smem + L_H))[i] = 0;
  for (int i = tid; i < 1024; i += 512) {
    int r = i & 3, mt = (i >> 2) & 7, lg_ = (i >> 5) & 3, w_ = i >> 7;
    int gt = mt >> 1, jt = mt & 1;
    int row = gt * 256 + 32 * w_ + 16 * jt + 4 * lg_ + r;
    ((float*)(smem + L_BIAS))[i] = bias[dir * 1024 + row];
  }
  __syncthreads();

  // per-wave W slice: frag f (= kt*8+mt) at wbase + f*1024 (+l*16 per lane)
  const char* wbase = (const char*)wpack + ((long)dir * 8 + w) * 81920 + (long)l * 16;
  const bf16x8* wp = reinterpret_cast<const bf16x8*>(wpack) +
                     ((long)dir * 8 + w) * 5120 + l;
  const char* xb = (const char*)xf + (long)bg * (128L * 2048) + (long)l * 16;
  char* const ringw = smem + L_RING + w * 16384;   // + slot*2048 + j*1024

  float* outp = out + ((long)s * 512 + dir * 256) * 8192 + a0 + ln;
  float cst[2][4] = {{0.f, 0.f, 0.f, 0.f}, {0.f, 0.f, 0.f, 0.f}};
  const int swz = (ln & 7) << 4;
  const int bias_off = ((w << 2) | lg) << 7;

  // streamed granule c (0..23): c<16 -> kt=6+(c>>2); else kt=(c-16)>>2.
  // frags mt = (c&3)*2 + {0,1}; ring slot = c&7.
#define ISSUE_G(c_) do {                                                \
    const int kt_ = ((c_) < 16) ? (6 + ((c_) >> 2)) : (((c_) - 16) >> 2); \
    const int f0_ = kt_ * 8 + ((c_) & 3) * 2;                           \
    gll16(wbase + (f0_ + 0) * 1024, ringw + ((c_) & 7) * 2048);         \
    gll16(wbase + (f0_ + 1) * 1024, ringw + ((c_) & 7) * 2048 + 1024);  \
  } while (0)

  // ---- prologue: persistent W (kt2..5) + ring prefill g0..g5 ----
  bf16x8 wreg[4][8];
#pragma unroll
  for (int kp = 0; kp < 4; ++kp)
#pragma unroll
    for (int mt = 0; mt < 8; ++mt) wreg[kp][mt] = wp[((kp + 2) * 8 + mt) * 64];
#pragma unroll
  for (int c = 0; c < 6; ++c) ISSUE_G(c);

  for (int st = 0; st < T_LEN; ++st) {
    const int t = dir ? (T_LEN - 1 - st) : st;

    // x fragments for THIS step (used in phase 5, ~2000cy away)
    bf16x8 bx0 = *reinterpret_cast<const bf16x8*>(xb + (long)t * 2048);
    bf16x8 bx1 = *reinterpret_cast<const bf16x8*>(xb + (long)t * 2048 + 1024);

    f32x4 acc[8];
#pragma unroll
    for (int mt = 0; mt < 8; ++mt)
      acc[mt] = *reinterpret_cast<const f32x4*>(smem + L_BIAS + bias_off + mt * 16);

    const char* hb = smem + L_H + 512 * ln;

    // ---- phase 2: persistent kt2..5 (register W, h tiles 0..3) ----
#pragma unroll
    for (int kp = 0; kp < 4; ++kp) {
      bf16x8 bh = *reinterpret_cast<const bf16x8*>(hb + ((kp * 64 + lg * 16) ^ swz));
#pragma unroll
      for (int mt = 0; mt < 8; ++mt)
        acc[mt] = __builtin_amdgcn_mfma_f32_16x16x32_bf16(wreg[kp][mt], bh, acc[mt], 0, 0, 0);
    }

    // ---- phase 3: ring kt6..9 (h tiles 4..7), granules 0..15 ----
    bf16x8 bh;
#pragma unroll
    for (int c = 0; c < 16; ++c) {
      ISSUE_G(c + 6);
      WAITV(12); SCHB;
      if ((c & 3) == 0)
        bh = *reinterpret_cast<const bf16x8*>(
            hb + (((4 + (c >> 2)) * 64 + lg * 16) ^ swz));
      bf16x8 wa0 = *reinterpret_cast<const bf16x8*>(ringw + (c & 7) * 2048 + l * 16);
      bf16x8 wa1 = *reinterpret_cast<const bf16x8*>(ringw + (c & 7) * 2048 + 1024 + l * 16);
      acc[(c & 3) * 2 + 0] = __builtin_amdgcn_mfma_f32_16x16x32_bf16(wa0, bh, acc[(c & 3) * 2 + 0], 0, 0, 0);
      acc[(c & 3) * 2 + 1] = __builtin_amdgcn_mfma_f32_16x16x32_bf16(wa1, bh, acc[(c & 3) * 2 + 1], 0, 0, 0);
    }

    // barrier A: all waves done reading h(t-1) (reads retired before MFMAs)
    SCHB; __builtin_amdgcn_s_barrier(); SCHB;

    // ---- phase 5: ring kt0,1 (input proj), granules 16..23 ----
#pragma unroll
    for (int c = 16; c < 24; ++c) {
      if (c == 16)      ISSUE_G(22);       // remaining proj granules
      else if (c == 17) ISSUE_G(23);
      else              ISSUE_G(c - 18);   // next step's g0..g5
      WAITV(12); SCHB;
      bf16x8 bx = (c < 20) ? bx0 : bx1;
      bf16x8 wa0 = *reinterpret_cast<const bf16x8*>(ringw + (c & 7) * 2048 + l * 16);
      bf16x8 wa1 = *reinterpret_cast<const bf16x8*>(ringw + (c & 7) * 2048 + 1024 + l * 16);
      acc[(c & 3) * 2 + 0] = __builtin_amdgcn_mfma_f32_16x16x32_bf16(wa0, bx, acc[(c & 3) * 2 + 0], 0, 0, 0);
      acc[(c & 3) * 2 + 1] = __builtin_amdgcn_mfma_f32_16x16x32_bf16(wa1, bx, acc[(c & 3) * 2 + 1], 0, 0, 0);
    }

    // ---- epilogue: gates -> c, h ----
    float hv[2][4];
#pragma unroll
    for (int jt = 0; jt < 2; ++jt) {
#pragma unroll
      for (int r = 0; r < 4; ++r) {
        float gi = sigmoidf_fast(acc[0 + jt][r]);
        float gf = sigmoidf_fast(acc[2 + jt][r]);
        float gg = tanhf_fast(acc[4 + jt][r]);
        float go = sigmoidf_fast(acc[6 + jt][r]);
        float cc = gf * cst[jt][r] + gi * gg;
        cst[jt][r] = cc;
        hv[jt][r] = go * tanhf_fast(cc);
      }
    }

    // h write (bf16, swizzled, 2x ds_write_b64), then barrier B
    {
      char* hw = smem + L_H + 512 * ln;
#pragma unroll
      for (int jt = 0; jt < 2; ++jt) {
        unsigned lo = (unsigned short)f32_to_bf16(hv[jt][0]) |
                      ((unsigned)(unsigned short)f32_to_bf16(hv[jt][1]) << 16);
        unsigned hi = (unsigned short)f32_to_bf16(hv[jt][2]) |
                      ((unsigned)(unsigned short)f32_to_bf16(hv[jt][3]) << 16);
        uint2v v = {lo, hi};
        *reinterpret_cast<uint2v*>(hw + ((64 * w + 32 * jt + 8 * lg) ^ swz)) = v;
      }
    }
    asm volatile("s_waitcnt lgkmcnt(0)" ::: "memory");
    __builtin_amdgcn_s_barrier();
    SCHB;

    // out stores (after barrier B; overlap next step's phases 1-2)
    {
      float* outt = outp + (long)t * 64;
#pragma unroll
      for (int jt = 0; jt < 2; ++jt)
#pragma unroll
        for (int r = 0; r < 4; ++r)
          outt[(long)(32 * w + 16 * jt + 4 * lg + r) * 8192] = hv[jt][r];
    }
  }
#undef ISSUE_G
}

// ---------------- launcher ----------------
extern "C" void kernel_launch(void* const* d_in, const int* in_sizes, int n_in,
                              void* d_out, int out_size, void* d_ws, size_t ws_size,
                              hipStream_t stream) {
  const float* x     = (const float*)d_in[0];
  const float* Wih_f = (const float*)d_in[1];
  const float* Whh_f = (const float*)d_in[2];
  const float* bih_f = (const float*)d_in[3];
  const float* bhh_f = (const float*)d_in[4];
  const float* Wih_b = (const float*)d_in[5];
  const float* Whh_b = (const float*)d_in[6];
  const float* bih_b = (const float*)d_in[7];
  const float* bhh_b = (const float*)d_in[8];
  float* out = (float*)d_out;

  char* ws = (char*)d_ws;
  short* wpack = (short*)(ws + WPACK_OFF);
  float* bias  = (float*)(ws + BIAS_OFF);
  short* xfb   = (short*)(ws + XF_OFF);

  static int smem_set = 0;
  if (!smem_set) {
    (void)hipFuncSetAttribute((const void*)lstm_rec,
                              hipFuncAttributeMaxDynamicSharedMemorySize, SMEM_BYTES);
    smem_set = 1;
  }

  hipLaunchKernelGGL(pack_w, dim3(320), dim3(256), 0, stream,
                     Wih_f, Whh_f, Wih_b, Whh_b, wpack);
  hipLaunchKernelGGL(pack_bias, dim3(8), dim3(256), 0, stream,
                     bih_f, bhh_f, bih_b, bhh_b, bias);
  hipLaunchKernelGGL(pack_x, dim3(4096), dim3(256), 0, stream, x, xfb);
  hipLaunchKernelGGL(lstm_rec, dim3(128), dim3(512), SMEM_BYTES, stream,
                     wpack, bias, xfb, out);
}